// Round 6
// baseline (454.180 us; speedup 1.0000x reference)
//
#include <hip/hip_runtime.h>
#include <math.h>

// Problem constants
#define M_ROWS 32768   // 32*32*32 positions
#define DIMS   256
#define KCODES 4096
#define NTILE  32      // column tiles of 128
#define EPS_C  0.5f    // collection window vs block-row-min (hh err max ~0.06)
#define EPS_R  1.25f   // refine window (covers EPS_C + f16 key rounding)

// ws layout (float units) — ~2.4 MB
#define WS_CH     0          // 4096*256 halves = 524288 floats (codebook hi f16)
#define WS_V2     524288     // 32768 floats ||v||^2 (fp32-exact)
#define WS_C2     557056     // 4096  floats ||c||^2
#define WS_COLKEY 561152     // 4096  u32 f32-bits colmin (entropy)
#define WS_TOKEN  565248     // 32768 u32 tokens
#define WS_PART   598016     // 8192 floats per-refine-block mse partials

// d_out scratch (overwritten by vq_gather at the end):
//   floats [0, 4194304)        : Vh    = 32768*256 f16
//   floats [4194304, 8388608)  : candG = 32768 rows * 32 tiles * 4 u32

typedef _Float16 half8 __attribute__((ext_vector_type(8)));
typedef _Float16 half4 __attribute__((ext_vector_type(4)));
typedef float floatx4 __attribute__((ext_vector_type(4)));

// ---------------------------------------------------------------------------
// prep: f16-hi conversion of V (-> d_out scratch) and CB (-> ws), exact fp32
// norms, plus colkey init (replaces memset).
__global__ __launch_bounds__(256) void vq_prep(const float* __restrict__ V,
                                               const float* __restrict__ CB,
                                               float* __restrict__ ws,
                                               float* __restrict__ outbuf) {
  if (blockIdx.x < 16)
    ((unsigned*)(ws + WS_COLKEY))[blockIdx.x * 256 + threadIdx.x] = 0xFFFFFFFFu;
  int w = threadIdx.x >> 6, lane = threadIdx.x & 63;
  int row = blockIdx.x * 4 + w;
  const float* src;
  _Float16* dst;
  float* nrm;
  if (row < M_ROWS) {
    src = V + (size_t)row * DIMS;
    dst = (_Float16*)outbuf + (size_t)row * DIMS;
    nrm = ws + WS_V2 + row;
  } else {
    int r = row - M_ROWS;
    src = CB + (size_t)r * DIMS;
    dst = (_Float16*)(ws + WS_CH) + (size_t)r * DIMS;
    nrm = ws + WS_C2 + r;
  }
  float4 v = ((const float4*)src)[lane];
  half4 h;
  h[0] = (_Float16)v.x; h[1] = (_Float16)v.y;
  h[2] = (_Float16)v.z; h[3] = (_Float16)v.w;
  *(half4*)(dst + lane * 4) = h;
  float s = v.x * v.x + v.y * v.y + v.z * v.z + v.w * v.w;
  #pragma unroll
  for (int off = 32; off > 0; off >>= 1) s += __shfl_down(s, off, 64);
  if (lane == 0) *nrm = s;
}

// ---------------------------------------------------------------------------
// hh GEMM, NO-LDS: 128x128 tile, 4 waves (2x2 of 64x64). Fragments load
// global->VGPR directly (K=256, A/B L2-resident; one frag wave-instr = 16
// rows x 64B contiguous). Register double-buffer over kc; ZERO barriers in
// the K-loop (round 5's 16 barrier drains over 8 kc were the stall).
// LDS only for the epilogue reductions.
__global__ __launch_bounds__(256) void vq_hh(const _Float16* __restrict__ Vh,
                                             const _Float16* __restrict__ Ch,
                                             const float* __restrict__ wsv2,
                                             const float* __restrict__ wsc2,
                                             unsigned* __restrict__ candG,
                                             unsigned* __restrict__ colkey) {
  __shared__ float v2s[128];
  __shared__ float c2s[128];
  __shared__ unsigned rowmin[128];
  __shared__ unsigned cnt[128];
  __shared__ unsigned candL[128][4];
  __shared__ float colM[2][128];

  const int t = threadIdx.x;
  const int lane = t & 63, w = t >> 6;
  const int wm = w & 1, wn = w >> 1;          // wave grid 2x2, each 64x64
  const int q = lane >> 4, c = lane & 15;
  const int rt = blockIdx.x >> 5, ct = blockIdx.x & 31;
  const int rowBase = rt * 128, colBase = ct * 128;

  if (t < 128) { v2s[t] = wsv2[rowBase + t]; rowmin[t] = 0xFFFFFFFFu; cnt[t] = 0u; }
  else         c2s[t - 128] = wsc2[colBase + (t - 128)];
  ((unsigned*)candL)[t] = 0xFFFFFFFFu;
  ((unsigned*)candL)[t + 256] = 0xFFFFFFFFu;
  // no barrier needed until epilogue: K-loop never touches LDS

  floatx4 acc[4][4];
  #pragma unroll
  for (int i = 0; i < 4; ++i)
    #pragma unroll
    for (int j = 0; j < 4; ++j) acc[i][j] = (floatx4){0.f, 0.f, 0.f, 0.f};

  // frag base addresses: lane (q,c), frag f -> row base+f*16+c, k = kc*32+q*8
  const _Float16* pa = Vh + (size_t)(rowBase + wm * 64 + c) * DIMS + q * 8;
  const _Float16* pb = Ch + (size_t)(colBase + wn * 64 + c) * DIMS + q * 8;

  half8 a[2][4], b[2][4];
  #pragma unroll
  for (int f = 0; f < 4; ++f) {
    a[0][f] = *(const half8*)(pa + f * (16 * DIMS));
    b[0][f] = *(const half8*)(pb + f * (16 * DIMS));
  }
  #pragma unroll
  for (int kc = 0; kc < 8; ++kc) {
    const int cur = kc & 1, nxt = cur ^ 1;
    if (kc < 7) {
      const _Float16* qa = pa + (kc + 1) * 32;
      const _Float16* qb = pb + (kc + 1) * 32;
      #pragma unroll
      for (int f = 0; f < 4; ++f) {
        a[nxt][f] = *(const half8*)(qa + f * (16 * DIMS));
        b[nxt][f] = *(const half8*)(qb + f * (16 * DIMS));
      }
    }
    #pragma unroll
    for (int fi = 0; fi < 4; ++fi)
      #pragma unroll
      for (int fj = 0; fj < 4; ++fj)
        acc[fi][fj] = __builtin_amdgcn_mfma_f32_16x16x32_f16(a[cur][fi], b[cur][fj], acc[fi][fj], 0, 0, 0);
  }

  __syncthreads();   // init writes (v2s/c2s/rowmin/cnt/candL) now visible

  // ---- phase 1: block-row-min + colmin ----
  float cm[4] = {3.4e38f, 3.4e38f, 3.4e38f, 3.4e38f};
  #pragma unroll
  for (int fi = 0; fi < 4; ++fi) {
    #pragma unroll
    for (int r = 0; r < 4; ++r) {
      int ml = wm * 64 + fi * 16 + q * 4 + r;
      float vv = v2s[ml];
      float mn = 3.4e38f;
      #pragma unroll
      for (int fj = 0; fj < 4; ++fj) {
        float d = vv + c2s[wn * 64 + fj * 16 + c] - 2.f * acc[fi][fj][r];
        cm[fj] = fminf(cm[fj], d);
        mn = fminf(mn, d);
      }
      mn = fminf(mn, __shfl_xor(mn, 1, 64));
      mn = fminf(mn, __shfl_xor(mn, 2, 64));
      mn = fminf(mn, __shfl_xor(mn, 4, 64));
      mn = fminf(mn, __shfl_xor(mn, 8, 64));
      if (c == 0) atomicMin(&rowmin[ml], __float_as_uint(mn));
    }
  }
  #pragma unroll
  for (int fj = 0; fj < 4; ++fj) {
    cm[fj] = fminf(cm[fj], __shfl_xor(cm[fj], 16, 64));
    cm[fj] = fminf(cm[fj], __shfl_xor(cm[fj], 32, 64));
  }
  if (lane < 16) {
    #pragma unroll
    for (int fj = 0; fj < 4; ++fj) colM[wm][wn * 64 + fj * 16 + c] = cm[fj];
  }
  __syncthreads();

  // ---- phase 2: collect candidates within rowmin + EPS_C ----
  #pragma unroll
  for (int fi = 0; fi < 4; ++fi) {
    #pragma unroll
    for (int r = 0; r < 4; ++r) {
      int ml = wm * 64 + fi * 16 + q * 4 + r;
      float thresh = __uint_as_float(rowmin[ml]) + EPS_C;
      float vv = v2s[ml];
      #pragma unroll
      for (int fj = 0; fj < 4; ++fj) {
        int nl = wn * 64 + fj * 16 + c;
        float d = vv + c2s[nl] - 2.f * acc[fi][fj][r];
        if (d <= thresh) {
          unsigned pos = atomicAdd(&cnt[ml], 1u);
          if (pos < 4) {
            unsigned short hb = __builtin_bit_cast(unsigned short, (_Float16)d);
            candL[ml][pos] = ((unsigned)hb << 16) | (unsigned)(colBase + nl);
          }
        }
      }
    }
  }
  __syncthreads();
  if (t < 128) {
    *(uint4*)(candG + ((size_t)(rowBase + t) * NTILE + ct) * 4) = *(uint4*)candL[t];
    float cv = fminf(colM[0][t], colM[1][t]);
    atomicMin(&colkey[colBase + t], __float_as_uint(cv));
  }
}

// ---------------------------------------------------------------------------
// refine: per row pick best f16 key; fp64-verify all candidates within EPS_R
// (rare). Also emits per-block mse partials (selected distance per row:
// exact fp64 on the verify path, f16-key approx otherwise — loss err ~1e-4).
__global__ __launch_bounds__(256) void vq_refine(const float* __restrict__ V,
                                                 const float* __restrict__ CB,
                                                 const unsigned* __restrict__ candG,
                                                 unsigned* __restrict__ token,
                                                 float* __restrict__ ws) {
  __shared__ float psum[4];
  int w = threadIdx.x >> 6, lane = threadIdx.x & 63;
  int row = blockIdx.x * 4 + w;
  const unsigned* cg = candG + (size_t)row * (NTILE * 4);
  unsigned e0 = cg[lane], e1 = cg[lane + 64];
  unsigned m = e0 < e1 ? e0 : e1;
  #pragma unroll
  for (int off = 1; off < 64; off <<= 1) {
    unsigned o = __shfl_xor(m, off, 64);
    m = (o < m) ? o : m;
  }
  float bestv = (float)__builtin_bit_cast(_Float16, (unsigned short)(m >> 16));
  float v0k = (float)__builtin_bit_cast(_Float16, (unsigned short)(e0 >> 16));
  float v1k = (float)__builtin_bit_cast(_Float16, (unsigned short)(e1 >> 16));
  // empty slots (0xFFFF) decode to NaN -> compare false -> excluded
  unsigned long long mask0 = __ballot(v0k <= bestv + EPS_R);
  unsigned long long mask1 = __ballot(v1k <= bestv + EPS_R);
  int tok = (int)(m & 0xFFFFu);
  float dsel = bestv;
  if (__popcll(mask0) + __popcll(mask1) > 1) {
    float4 x = ((const float4*)(V + (size_t)row * DIMS))[lane];
    double bd = 1e300; int bi = 0x7FFFFFFF;
    #pragma unroll
    for (int h = 0; h < 2; ++h) {
      unsigned long long mask = h ? mask1 : mask0;
      unsigned ee = h ? e1 : e0;
      while (mask) {
        int l = __ffsll((unsigned long long)mask) - 1;
        mask &= mask - 1;
        int idx = (int)(__shfl(ee, l, 64) & 0xFFFFu);
        float4 cv = ((const float4*)(CB + (size_t)idx * DIMS))[lane];
        double dx = (double)cv.x - (double)x.x;
        double dy = (double)cv.y - (double)x.y;
        double dz = (double)cv.z - (double)x.z;
        double dw = (double)cv.w - (double)x.w;
        double s = dx * dx + dy * dy + dz * dz + dw * dw;
        #pragma unroll
        for (int off = 1; off < 64; off <<= 1) s += __shfl_xor(s, off, 64);
        if (s < bd || (s == bd && idx < bi)) { bd = s; bi = idx; }
      }
    }
    tok = bi;
    dsel = (float)bd;
  }
  if (lane == 0) { token[row] = (unsigned)tok; psum[w] = dsel; }
  __syncthreads();
  if (threadIdx.x == 0)
    ws[WS_PART + blockIdx.x] = psum[0] + psum[1] + psum[2] + psum[3];
}

// ---------------------------------------------------------------------------
// gather: out = x + (e - x). Block 0 additionally computes the loss from
// refine's mse partials + colkeys (all in ws, complete at kernel boundary —
// no fence, no atomics).
__global__ __launch_bounds__(256) void vq_gather(const float* __restrict__ V,
                                                 const float* __restrict__ CB,
                                                 const unsigned* __restrict__ token,
                                                 const float* __restrict__ ws,
                                                 float* __restrict__ out) {
  int w = threadIdx.x >> 6, lane = threadIdx.x & 63;
  int row = blockIdx.x * 4 + w;
  int tok = (int)token[row];

  float4 e = *(const float4*)(CB + (size_t)tok * DIMS + lane * 4);
  float4 x = *(const float4*)(V + (size_t)row * DIMS + lane * 4);
  float4 o;
  o.x = x.x + (e.x - x.x); o.y = x.y + (e.y - x.y);
  o.z = x.z + (e.z - x.z); o.w = x.w + (e.w - x.w);
  *(float4*)(out + (size_t)row * DIMS + lane * 4) = o;

  if (blockIdx.x == 0) {
    __shared__ float psum[4];
    float s = 0.f;
    for (int i = threadIdx.x; i < 8192; i += 256) s += ws[WS_PART + i];
    const unsigned* ck = (const unsigned*)(ws + WS_COLKEY);
    float cs = 0.f;
    for (int i = threadIdx.x; i < KCODES; i += 256) cs += __uint_as_float(ck[i]);
    float v = s * (1.25f / 8388608.f) + cs * (0.1f / 4096.f);
    #pragma unroll
    for (int off = 32; off > 0; off >>= 1) v += __shfl_down(v, off, 64);
    if (lane == 0) psum[w] = v;
    __syncthreads();
    if (threadIdx.x == 0)
      out[8388608] = psum[0] + psum[1] + psum[2] + psum[3];
  }
}

// ---------------------------------------------------------------------------
extern "C" void kernel_launch(void* const* d_in, const int* in_sizes, int n_in,
                              void* d_out, int out_size, void* d_ws, size_t ws_size,
                              hipStream_t stream) {
  const float* V  = (const float*)d_in[0];   // [32768, 256]
  const float* CB = (const float*)d_in[1];   // [4096, 256]
  float* out = (float*)d_out;                // 8388608 emb + 1 loss
  float* ws  = (float*)d_ws;

  _Float16* Vh     = (_Float16*)out;                 // scratch in d_out
  unsigned* candG  = (unsigned*)(out + 4194304);     // scratch in d_out (16 MB)
  unsigned* colkey = (unsigned*)(ws + WS_COLKEY);
  unsigned* token  = (unsigned*)(ws + WS_TOKEN);

  vq_prep<<<(M_ROWS + KCODES) / 4, 256, 0, stream>>>(V, CB, ws, out);
  vq_hh<<<8192, 256, 0, stream>>>(Vh, (const _Float16*)(ws + WS_CH),
                                  ws + WS_V2, ws + WS_C2, candG, colkey);
  vq_refine<<<M_ROWS / 4, 256, 0, stream>>>(V, CB, candG, token, ws);
  vq_gather<<<M_ROWS / 4, 256, 0, stream>>>(V, CB, token, ws, out);
}

// Round 7
// 298.180 us; speedup vs baseline: 1.5232x; 1.5232x over previous
//
#include <hip/hip_runtime.h>
#include <math.h>

// Problem constants
#define M_ROWS 32768   // 32*32*32 positions
#define DIMS   256
#define KCODES 4096
#define NTILE  32      // column tiles of 128
#define EPS_C  0.5f    // collection window vs block-row-min (hh err max ~0.06)
#define EPS_R  1.25f   // refine window (covers EPS_C + f16 key rounding)

// ws layout (float units) — ~2.4 MB
#define WS_CH     0          // 4096*256 halves (codebook, MFMA-tiled layout)
#define WS_V2     524288     // 32768 floats ||v||^2 (fp32-exact)
#define WS_C2     557056     // 4096  floats ||c||^2
#define WS_COLKEY 561152     // 4096  u32 f32-bits colmin (entropy)
#define WS_TOKEN  565248     // 32768 u32 tokens
#define WS_PART   598016     // 8192 floats per-refine-block mse partials

// d_out scratch (overwritten by vq_gather at the end):
//   floats [0, 4194304)        : Vh    = 32768*256 f16 (MFMA-tiled layout)
//   floats [4194304, 8388608)  : candG = 32768 rows * 32 tiles * 4 u32
//
// Tiled layout (both Vh and Ch): rows grouped in 16-row panels p; halves
// k-grouped by (kc 0..7, q 0..3). Chunk = 8 halves (16B):
//   chunk_index(p, kc, q, c) = (p*8 + kc)*64 + q*16 + c      (c = row % 16)
// A wave's frag load (lane = q*16+c) then reads 64 CONSECUTIVE chunks
// = one coalesced 1KB transaction. (Round 6 stored row-major: each frag
// load scattered to 16 segments at 512B stride -> TA serialization, 361us.)

typedef _Float16 half8 __attribute__((ext_vector_type(8)));
typedef _Float16 half4 __attribute__((ext_vector_type(4)));
typedef float floatx4 __attribute__((ext_vector_type(4)));

#define PANEL_H 4096   // halves per 16-row panel (16*256)

// ---------------------------------------------------------------------------
// prep: f16-hi conversion of V (-> d_out scratch) and CB (-> ws) into the
// MFMA-tiled layout, exact fp32 norms, colkey init.
__global__ __launch_bounds__(256) void vq_prep(const float* __restrict__ V,
                                               const float* __restrict__ CB,
                                               float* __restrict__ ws,
                                               float* __restrict__ outbuf) {
  if (blockIdx.x < 16)
    ((unsigned*)(ws + WS_COLKEY))[blockIdx.x * 256 + threadIdx.x] = 0xFFFFFFFFu;
  int w = threadIdx.x >> 6, lane = threadIdx.x & 63;
  int row = blockIdx.x * 4 + w;
  const float* src;
  _Float16* dst;
  float* nrm;
  int rl;
  if (row < M_ROWS) {
    rl  = row;
    src = V + (size_t)row * DIMS;
    dst = (_Float16*)outbuf;
    nrm = ws + WS_V2 + row;
  } else {
    rl  = row - M_ROWS;
    src = CB + (size_t)rl * DIMS;
    dst = (_Float16*)(ws + WS_CH);
    nrm = ws + WS_C2 + rl;
  }
  float4 v = ((const float4*)src)[lane];
  half4 h;
  h[0] = (_Float16)v.x; h[1] = (_Float16)v.y;
  h[2] = (_Float16)v.z; h[3] = (_Float16)v.w;
  // tiled address: floats k0=lane*4 -> kc=lane>>3, q=(lane>>1)&3, hi=(lane&1)*4
  {
    int p = rl >> 4, cc = rl & 15;
    int kc = lane >> 3, q = (lane >> 1) & 3, hi = (lane & 1) * 4;
    size_t off = (((size_t)p * 8 + kc) * 64 + q * 16 + cc) * 8 + hi;
    *(half4*)(dst + off) = h;
  }
  float s = v.x * v.x + v.y * v.y + v.z * v.z + v.w * v.w;
  #pragma unroll
  for (int off = 32; off > 0; off >>= 1) s += __shfl_down(s, off, 64);
  if (lane == 0) *nrm = s;
}

// ---------------------------------------------------------------------------
// hh GEMM, tiled direct-load: 128x128 tile, 4 waves (2x2 of 64x64). Fragment
// loads are 1KB coalesced global reads from the tiled Vh/Ch (L2-resident).
// Register double-buffer over kc; ZERO barriers / LDS in the K-loop.
__global__ __launch_bounds__(256) void vq_hh(const _Float16* __restrict__ Vh,
                                             const _Float16* __restrict__ Ch,
                                             const float* __restrict__ wsv2,
                                             const float* __restrict__ wsc2,
                                             unsigned* __restrict__ candG,
                                             unsigned* __restrict__ colkey) {
  __shared__ float v2s[128];
  __shared__ float c2s[128];
  __shared__ unsigned rowmin[128];
  __shared__ unsigned cnt[128];
  __shared__ unsigned candL[128][4];
  __shared__ float colM[2][128];

  const int t = threadIdx.x;
  const int lane = t & 63, w = t >> 6;
  const int wm = w & 1, wn = w >> 1;          // wave grid 2x2, each 64x64
  const int q = lane >> 4, c = lane & 15;
  const int rt = blockIdx.x >> 5, ct = blockIdx.x & 31;
  const int rowBase = rt * 128, colBase = ct * 128;

  if (t < 128) { v2s[t] = wsv2[rowBase + t]; rowmin[t] = 0xFFFFFFFFu; cnt[t] = 0u; }
  else         c2s[t - 128] = wsc2[colBase + (t - 128)];
  ((unsigned*)candL)[t] = 0xFFFFFFFFu;
  ((unsigned*)candL)[t + 256] = 0xFFFFFFFFu;
  // no barrier needed until epilogue: K-loop never touches LDS

  floatx4 acc[4][4];
  #pragma unroll
  for (int i = 0; i < 4; ++i)
    #pragma unroll
    for (int j = 0; j < 4; ++j) acc[i][j] = (floatx4){0.f, 0.f, 0.f, 0.f};

  // frag base: panel pA+f, lane offset = lane*8 halves within the 1KB chunk-run
  const int pA = (rowBase >> 4) + wm * 4;
  const int pB = (colBase >> 4) + wn * 4;
  const _Float16* baseA = Vh + (size_t)pA * PANEL_H + lane * 8;
  const _Float16* baseB = Ch + (size_t)pB * PANEL_H + lane * 8;

  half8 a[2][4], b[2][4];
  #pragma unroll
  for (int f = 0; f < 4; ++f) {
    a[0][f] = *(const half8*)(baseA + (size_t)f * PANEL_H);
    b[0][f] = *(const half8*)(baseB + (size_t)f * PANEL_H);
  }
  #pragma unroll
  for (int kc = 0; kc < 8; ++kc) {
    const int cur = kc & 1, nxt = cur ^ 1;
    if (kc < 7) {
      const _Float16* qa = baseA + (kc + 1) * 512;
      const _Float16* qb = baseB + (kc + 1) * 512;
      #pragma unroll
      for (int f = 0; f < 4; ++f) {
        a[nxt][f] = *(const half8*)(qa + (size_t)f * PANEL_H);
        b[nxt][f] = *(const half8*)(qb + (size_t)f * PANEL_H);
      }
    }
    #pragma unroll
    for (int fi = 0; fi < 4; ++fi)
      #pragma unroll
      for (int fj = 0; fj < 4; ++fj)
        acc[fi][fj] = __builtin_amdgcn_mfma_f32_16x16x32_f16(a[cur][fi], b[cur][fj], acc[fi][fj], 0, 0, 0);
  }

  __syncthreads();   // init writes (v2s/c2s/rowmin/cnt/candL) now visible

  // ---- phase 1: block-row-min + colmin ----
  float cm[4] = {3.4e38f, 3.4e38f, 3.4e38f, 3.4e38f};
  #pragma unroll
  for (int fi = 0; fi < 4; ++fi) {
    #pragma unroll
    for (int r = 0; r < 4; ++r) {
      int ml = wm * 64 + fi * 16 + q * 4 + r;
      float vv = v2s[ml];
      float mn = 3.4e38f;
      #pragma unroll
      for (int fj = 0; fj < 4; ++fj) {
        float d = vv + c2s[wn * 64 + fj * 16 + c] - 2.f * acc[fi][fj][r];
        cm[fj] = fminf(cm[fj], d);
        mn = fminf(mn, d);
      }
      mn = fminf(mn, __shfl_xor(mn, 1, 64));
      mn = fminf(mn, __shfl_xor(mn, 2, 64));
      mn = fminf(mn, __shfl_xor(mn, 4, 64));
      mn = fminf(mn, __shfl_xor(mn, 8, 64));
      if (c == 0) atomicMin(&rowmin[ml], __float_as_uint(mn));
    }
  }
  #pragma unroll
  for (int fj = 0; fj < 4; ++fj) {
    cm[fj] = fminf(cm[fj], __shfl_xor(cm[fj], 16, 64));
    cm[fj] = fminf(cm[fj], __shfl_xor(cm[fj], 32, 64));
  }
  if (lane < 16) {
    #pragma unroll
    for (int fj = 0; fj < 4; ++fj) colM[wm][wn * 64 + fj * 16 + c] = cm[fj];
  }
  __syncthreads();

  // ---- phase 2: collect candidates within rowmin + EPS_C ----
  #pragma unroll
  for (int fi = 0; fi < 4; ++fi) {
    #pragma unroll
    for (int r = 0; r < 4; ++r) {
      int ml = wm * 64 + fi * 16 + q * 4 + r;
      float thresh = __uint_as_float(rowmin[ml]) + EPS_C;
      float vv = v2s[ml];
      #pragma unroll
      for (int fj = 0; fj < 4; ++fj) {
        int nl = wn * 64 + fj * 16 + c;
        float d = vv + c2s[nl] - 2.f * acc[fi][fj][r];
        if (d <= thresh) {
          unsigned pos = atomicAdd(&cnt[ml], 1u);
          if (pos < 4) {
            unsigned short hb = __builtin_bit_cast(unsigned short, (_Float16)d);
            candL[ml][pos] = ((unsigned)hb << 16) | (unsigned)(colBase + nl);
          }
        }
      }
    }
  }
  __syncthreads();
  if (t < 128) {
    *(uint4*)(candG + ((size_t)(rowBase + t) * NTILE + ct) * 4) = *(uint4*)candL[t];
    float cv = fminf(colM[0][t], colM[1][t]);
    atomicMin(&colkey[colBase + t], __float_as_uint(cv));
  }
}

// ---------------------------------------------------------------------------
// refine: per row pick best f16 key; fp64-verify all candidates within EPS_R
// (rare). Also emits per-block mse partials (selected distance per row:
// exact fp64 on the verify path, f16-key approx otherwise — loss err ~1e-4).
__global__ __launch_bounds__(256) void vq_refine(const float* __restrict__ V,
                                                 const float* __restrict__ CB,
                                                 const unsigned* __restrict__ candG,
                                                 unsigned* __restrict__ token,
                                                 float* __restrict__ ws) {
  __shared__ float psum[4];
  int w = threadIdx.x >> 6, lane = threadIdx.x & 63;
  int row = blockIdx.x * 4 + w;
  const unsigned* cg = candG + (size_t)row * (NTILE * 4);
  unsigned e0 = cg[lane], e1 = cg[lane + 64];
  unsigned m = e0 < e1 ? e0 : e1;
  #pragma unroll
  for (int off = 1; off < 64; off <<= 1) {
    unsigned o = __shfl_xor(m, off, 64);
    m = (o < m) ? o : m;
  }
  float bestv = (float)__builtin_bit_cast(_Float16, (unsigned short)(m >> 16));
  float v0k = (float)__builtin_bit_cast(_Float16, (unsigned short)(e0 >> 16));
  float v1k = (float)__builtin_bit_cast(_Float16, (unsigned short)(e1 >> 16));
  // empty slots (0xFFFF) decode to NaN -> compare false -> excluded
  unsigned long long mask0 = __ballot(v0k <= bestv + EPS_R);
  unsigned long long mask1 = __ballot(v1k <= bestv + EPS_R);
  int tok = (int)(m & 0xFFFFu);
  float dsel = bestv;
  if (__popcll(mask0) + __popcll(mask1) > 1) {
    float4 x = ((const float4*)(V + (size_t)row * DIMS))[lane];
    double bd = 1e300; int bi = 0x7FFFFFFF;
    #pragma unroll
    for (int h = 0; h < 2; ++h) {
      unsigned long long mask = h ? mask1 : mask0;
      unsigned ee = h ? e1 : e0;
      while (mask) {
        int l = __ffsll((unsigned long long)mask) - 1;
        mask &= mask - 1;
        int idx = (int)(__shfl(ee, l, 64) & 0xFFFFu);
        float4 cv = ((const float4*)(CB + (size_t)idx * DIMS))[lane];
        double dx = (double)cv.x - (double)x.x;
        double dy = (double)cv.y - (double)x.y;
        double dz = (double)cv.z - (double)x.z;
        double dw = (double)cv.w - (double)x.w;
        double s = dx * dx + dy * dy + dz * dz + dw * dw;
        #pragma unroll
        for (int off = 1; off < 64; off <<= 1) s += __shfl_xor(s, off, 64);
        if (s < bd || (s == bd && idx < bi)) { bd = s; bi = idx; }
      }
    }
    tok = bi;
    dsel = (float)bd;
  }
  if (lane == 0) { token[row] = (unsigned)tok; psum[w] = dsel; }
  __syncthreads();
  if (threadIdx.x == 0)
    ws[WS_PART + blockIdx.x] = psum[0] + psum[1] + psum[2] + psum[3];
}

// ---------------------------------------------------------------------------
// gather: out = x + (e - x). Block 0 additionally computes the loss from
// refine's mse partials + colkeys (all in ws, complete at kernel boundary).
__global__ __launch_bounds__(256) void vq_gather(const float* __restrict__ V,
                                                 const float* __restrict__ CB,
                                                 const unsigned* __restrict__ token,
                                                 const float* __restrict__ ws,
                                                 float* __restrict__ out) {
  int w = threadIdx.x >> 6, lane = threadIdx.x & 63;
  int row = blockIdx.x * 4 + w;
  int tok = (int)token[row];

  float4 e = *(const float4*)(CB + (size_t)tok * DIMS + lane * 4);
  float4 x = *(const float4*)(V + (size_t)row * DIMS + lane * 4);
  float4 o;
  o.x = x.x + (e.x - x.x); o.y = x.y + (e.y - x.y);
  o.z = x.z + (e.z - x.z); o.w = x.w + (e.w - x.w);
  *(float4*)(out + (size_t)row * DIMS + lane * 4) = o;

  if (blockIdx.x == 0) {
    __shared__ float psum[4];
    float s = 0.f;
    for (int i = threadIdx.x; i < 8192; i += 256) s += ws[WS_PART + i];
    const unsigned* ck = (const unsigned*)(ws + WS_COLKEY);
    float cs = 0.f;
    for (int i = threadIdx.x; i < KCODES; i += 256) cs += __uint_as_float(ck[i]);
    float v = s * (1.25f / 8388608.f) + cs * (0.1f / 4096.f);
    #pragma unroll
    for (int off = 32; off > 0; off >>= 1) v += __shfl_down(v, off, 64);
    if (lane == 0) psum[w] = v;
    __syncthreads();
    if (threadIdx.x == 0)
      out[8388608] = psum[0] + psum[1] + psum[2] + psum[3];
  }
}

// ---------------------------------------------------------------------------
extern "C" void kernel_launch(void* const* d_in, const int* in_sizes, int n_in,
                              void* d_out, int out_size, void* d_ws, size_t ws_size,
                              hipStream_t stream) {
  const float* V  = (const float*)d_in[0];   // [32768, 256]
  const float* CB = (const float*)d_in[1];   // [4096, 256]
  float* out = (float*)d_out;                // 8388608 emb + 1 loss
  float* ws  = (float*)d_ws;

  _Float16* Vh     = (_Float16*)out;                 // scratch in d_out (tiled)
  unsigned* candG  = (unsigned*)(out + 4194304);     // scratch in d_out (16 MB)
  unsigned* colkey = (unsigned*)(ws + WS_COLKEY);
  unsigned* token  = (unsigned*)(ws + WS_TOKEN);

  vq_prep<<<(M_ROWS + KCODES) / 4, 256, 0, stream>>>(V, CB, ws, out);
  vq_hh<<<8192, 256, 0, stream>>>(Vh, (const _Float16*)(ws + WS_CH),
                                  ws + WS_V2, ws + WS_C2, candG, colkey);
  vq_refine<<<M_ROWS / 4, 256, 0, stream>>>(V, CB, candG, token, ws);
  vq_gather<<<M_ROWS / 4, 256, 0, stream>>>(V, CB, token, ws, out);
}

// Round 8
// 290.811 us; speedup vs baseline: 1.5618x; 1.0253x over previous
//
#include <hip/hip_runtime.h>
#include <math.h>

// Problem constants
#define M_ROWS 32768   // 32*32*32 positions
#define DIMS   256
#define KCODES 4096
#define NTILE  32      // column tiles of 128
#define EPS_C  0.5f    // collection window vs block-row-min (hh err max ~0.06)
#define EPS_R  1.25f   // refine window (covers EPS_C + f16 key rounding)

// ws layout (float units) — ~2.4 MB
#define WS_CH     0          // 4096*256 halves (codebook, MFMA-tiled layout)
#define WS_V2     524288     // 32768 floats ||v||^2 (fp32-exact)
#define WS_C2     557056     // 4096  floats ||c||^2
#define WS_COLKEY 561152     // 4096  u32 f32-bits colmin (entropy)
#define WS_TOKEN  565248     // 32768 u32 tokens
#define WS_PART   598016     // 8192 floats per-refine-block mse partials

// d_out scratch (overwritten by vq_gather at the end):
//   floats [0, 4194304)        : Vh    = 32768*256 f16 (MFMA-tiled layout)
//   floats [4194304, 8388608)  : candG = 32768 rows * 32 tiles * 4 u32
//
// Tiled layout (both Vh and Ch): rows grouped in 16-row panels p; halves
// k-grouped by (kc 0..7, q 0..3). Chunk = 8 halves (16B):
//   chunk_index(p, kc, q, c) = (p*8 + kc)*64 + q*16 + c      (c = row % 16)
// A wave's frag load (lane = q*16+c) reads 64 CONSECUTIVE chunks = one
// coalesced 1KB transaction.

typedef _Float16 half8 __attribute__((ext_vector_type(8)));
typedef _Float16 half4 __attribute__((ext_vector_type(4)));
typedef float floatx4 __attribute__((ext_vector_type(4)));

#define PANEL_H 4096   // halves per 16-row panel (16*256)

// ---------------------------------------------------------------------------
// prep: f16-hi conversion of V (-> d_out scratch) and CB (-> ws) into the
// MFMA-tiled layout, exact fp32 norms, colkey init.
__global__ __launch_bounds__(256) void vq_prep(const float* __restrict__ V,
                                               const float* __restrict__ CB,
                                               float* __restrict__ ws,
                                               float* __restrict__ outbuf) {
  if (blockIdx.x < 16)
    ((unsigned*)(ws + WS_COLKEY))[blockIdx.x * 256 + threadIdx.x] = 0xFFFFFFFFu;
  int w = threadIdx.x >> 6, lane = threadIdx.x & 63;
  int row = blockIdx.x * 4 + w;
  const float* src;
  _Float16* dst;
  float* nrm;
  int rl;
  if (row < M_ROWS) {
    rl  = row;
    src = V + (size_t)row * DIMS;
    dst = (_Float16*)outbuf;
    nrm = ws + WS_V2 + row;
  } else {
    rl  = row - M_ROWS;
    src = CB + (size_t)rl * DIMS;
    dst = (_Float16*)(ws + WS_CH);
    nrm = ws + WS_C2 + rl;
  }
  float4 v = ((const float4*)src)[lane];
  half4 h;
  h[0] = (_Float16)v.x; h[1] = (_Float16)v.y;
  h[2] = (_Float16)v.z; h[3] = (_Float16)v.w;
  // tiled address: floats k0=lane*4 -> kc=lane>>3, q=(lane>>1)&3, hi=(lane&1)*4
  {
    int p = rl >> 4, cc = rl & 15;
    int kc = lane >> 3, q = (lane >> 1) & 3, hi = (lane & 1) * 4;
    size_t off = (((size_t)p * 8 + kc) * 64 + q * 16 + cc) * 8 + hi;
    *(half4*)(dst + off) = h;
  }
  float s = v.x * v.x + v.y * v.y + v.z * v.z + v.w * v.w;
  #pragma unroll
  for (int off = 32; off > 0; off >>= 1) s += __shfl_down(s, off, 64);
  if (lane == 0) *nrm = s;
}

// ---------------------------------------------------------------------------
// hh GEMM, tiled direct-load: 128x128 tile, 4 waves (2x2 of 64x64).
// launch_bounds(256,3): round 7 ran 2 waves/SIMD (124 arch + 64 acc = 188
// regs); capping at ~170 restores 3 waves/SIMD for latency cover. Single
// operand buffer — the compiler pipelines across the unrolled kc loop up to
// the register budget. Swizzled grid: rt = b&255, ct = b>>8, so 256
// consecutive blocks share one 64KB B tile (XCD-L2 / L1 hot).
__global__ __launch_bounds__(256, 3) void vq_hh(const _Float16* __restrict__ Vh,
                                                const _Float16* __restrict__ Ch,
                                                const float* __restrict__ wsv2,
                                                const float* __restrict__ wsc2,
                                                unsigned* __restrict__ candG,
                                                unsigned* __restrict__ colkey) {
  __shared__ float v2s[128];
  __shared__ float c2s[128];
  __shared__ unsigned rowmin[128];
  __shared__ unsigned cnt[128];
  __shared__ unsigned candL[128][4];
  __shared__ float colM[2][128];

  const int t = threadIdx.x;
  const int lane = t & 63, w = t >> 6;
  const int wm = w & 1, wn = w >> 1;          // wave grid 2x2, each 64x64
  const int q = lane >> 4, c = lane & 15;
  const int rt = blockIdx.x & 255, ct = blockIdx.x >> 8;
  const int rowBase = rt * 128, colBase = ct * 128;

  if (t < 128) { v2s[t] = wsv2[rowBase + t]; rowmin[t] = 0xFFFFFFFFu; cnt[t] = 0u; }
  else         c2s[t - 128] = wsc2[colBase + (t - 128)];
  ((unsigned*)candL)[t] = 0xFFFFFFFFu;
  ((unsigned*)candL)[t + 256] = 0xFFFFFFFFu;
  // no barrier needed until epilogue: K-loop never touches LDS

  floatx4 acc[4][4];
  #pragma unroll
  for (int i = 0; i < 4; ++i)
    #pragma unroll
    for (int j = 0; j < 4; ++j) acc[i][j] = (floatx4){0.f, 0.f, 0.f, 0.f};

  // frag base: panel pA+f, lane offset = lane*8 halves within the 1KB chunk-run
  const int pA = (rowBase >> 4) + wm * 4;
  const int pB = (colBase >> 4) + wn * 4;
  const _Float16* baseA = Vh + (size_t)pA * PANEL_H + lane * 8;
  const _Float16* baseB = Ch + (size_t)pB * PANEL_H + lane * 8;

  #pragma unroll
  for (int kc = 0; kc < 8; ++kc) {
    half8 a[4], b[4];
    #pragma unroll
    for (int f = 0; f < 4; ++f) {
      a[f] = *(const half8*)(baseA + kc * 512 + (size_t)f * PANEL_H);
      b[f] = *(const half8*)(baseB + kc * 512 + (size_t)f * PANEL_H);
    }
    #pragma unroll
    for (int fi = 0; fi < 4; ++fi)
      #pragma unroll
      for (int fj = 0; fj < 4; ++fj)
        acc[fi][fj] = __builtin_amdgcn_mfma_f32_16x16x32_f16(a[fi], b[fj], acc[fi][fj], 0, 0, 0);
  }

  __syncthreads();   // init writes (v2s/c2s/rowmin/cnt/candL) now visible

  // ---- phase 1: block-row-min + colmin ----
  float cm[4] = {3.4e38f, 3.4e38f, 3.4e38f, 3.4e38f};
  #pragma unroll
  for (int fi = 0; fi < 4; ++fi) {
    #pragma unroll
    for (int r = 0; r < 4; ++r) {
      int ml = wm * 64 + fi * 16 + q * 4 + r;
      float vv = v2s[ml];
      float mn = 3.4e38f;
      #pragma unroll
      for (int fj = 0; fj < 4; ++fj) {
        float d = vv + c2s[wn * 64 + fj * 16 + c] - 2.f * acc[fi][fj][r];
        cm[fj] = fminf(cm[fj], d);
        mn = fminf(mn, d);
      }
      mn = fminf(mn, __shfl_xor(mn, 1, 64));
      mn = fminf(mn, __shfl_xor(mn, 2, 64));
      mn = fminf(mn, __shfl_xor(mn, 4, 64));
      mn = fminf(mn, __shfl_xor(mn, 8, 64));
      if (c == 0) atomicMin(&rowmin[ml], __float_as_uint(mn));
    }
  }
  #pragma unroll
  for (int fj = 0; fj < 4; ++fj) {
    cm[fj] = fminf(cm[fj], __shfl_xor(cm[fj], 16, 64));
    cm[fj] = fminf(cm[fj], __shfl_xor(cm[fj], 32, 64));
  }
  if (lane < 16) {
    #pragma unroll
    for (int fj = 0; fj < 4; ++fj) colM[wm][wn * 64 + fj * 16 + c] = cm[fj];
  }
  __syncthreads();

  // ---- phase 2: collect candidates within rowmin + EPS_C ----
  #pragma unroll
  for (int fi = 0; fi < 4; ++fi) {
    #pragma unroll
    for (int r = 0; r < 4; ++r) {
      int ml = wm * 64 + fi * 16 + q * 4 + r;
      float thresh = __uint_as_float(rowmin[ml]) + EPS_C;
      float vv = v2s[ml];
      #pragma unroll
      for (int fj = 0; fj < 4; ++fj) {
        int nl = wn * 64 + fj * 16 + c;
        float d = vv + c2s[nl] - 2.f * acc[fi][fj][r];
        if (d <= thresh) {
          unsigned pos = atomicAdd(&cnt[ml], 1u);
          if (pos < 4) {
            unsigned short hb = __builtin_bit_cast(unsigned short, (_Float16)d);
            candL[ml][pos] = ((unsigned)hb << 16) | (unsigned)(colBase + nl);
          }
        }
      }
    }
  }
  __syncthreads();
  if (t < 128) {
    *(uint4*)(candG + ((size_t)(rowBase + t) * NTILE + ct) * 4) = *(uint4*)candL[t];
    float cv = fminf(colM[0][t], colM[1][t]);
    atomicMin(&colkey[colBase + t], __float_as_uint(cv));
  }
}

// ---------------------------------------------------------------------------
// refine: per row pick best f16 key; fp64-verify all candidates within EPS_R
// (rare). Also emits per-block mse partials (selected distance per row:
// exact fp64 on the verify path, f16-key approx otherwise — loss err ~1e-4).
__global__ __launch_bounds__(256) void vq_refine(const float* __restrict__ V,
                                                 const float* __restrict__ CB,
                                                 const unsigned* __restrict__ candG,
                                                 unsigned* __restrict__ token,
                                                 float* __restrict__ ws) {
  __shared__ float psum[4];
  int w = threadIdx.x >> 6, lane = threadIdx.x & 63;
  int row = blockIdx.x * 4 + w;
  const unsigned* cg = candG + (size_t)row * (NTILE * 4);
  unsigned e0 = cg[lane], e1 = cg[lane + 64];
  unsigned m = e0 < e1 ? e0 : e1;
  #pragma unroll
  for (int off = 1; off < 64; off <<= 1) {
    unsigned o = __shfl_xor(m, off, 64);
    m = (o < m) ? o : m;
  }
  float bestv = (float)__builtin_bit_cast(_Float16, (unsigned short)(m >> 16));
  float v0k = (float)__builtin_bit_cast(_Float16, (unsigned short)(e0 >> 16));
  float v1k = (float)__builtin_bit_cast(_Float16, (unsigned short)(e1 >> 16));
  // empty slots (0xFFFF) decode to NaN -> compare false -> excluded
  unsigned long long mask0 = __ballot(v0k <= bestv + EPS_R);
  unsigned long long mask1 = __ballot(v1k <= bestv + EPS_R);
  int tok = (int)(m & 0xFFFFu);
  float dsel = bestv;
  if (__popcll(mask0) + __popcll(mask1) > 1) {
    float4 x = ((const float4*)(V + (size_t)row * DIMS))[lane];
    double bd = 1e300; int bi = 0x7FFFFFFF;
    #pragma unroll
    for (int h = 0; h < 2; ++h) {
      unsigned long long mask = h ? mask1 : mask0;
      unsigned ee = h ? e1 : e0;
      while (mask) {
        int l = __ffsll((unsigned long long)mask) - 1;
        mask &= mask - 1;
        int idx = (int)(__shfl(ee, l, 64) & 0xFFFFu);
        float4 cv = ((const float4*)(CB + (size_t)idx * DIMS))[lane];
        double dx = (double)cv.x - (double)x.x;
        double dy = (double)cv.y - (double)x.y;
        double dz = (double)cv.z - (double)x.z;
        double dw = (double)cv.w - (double)x.w;
        double s = dx * dx + dy * dy + dz * dz + dw * dw;
        #pragma unroll
        for (int off = 1; off < 64; off <<= 1) s += __shfl_xor(s, off, 64);
        if (s < bd || (s == bd && idx < bi)) { bd = s; bi = idx; }
      }
    }
    tok = bi;
    dsel = (float)bd;
  }
  if (lane == 0) { token[row] = (unsigned)tok; psum[w] = dsel; }
  __syncthreads();
  if (threadIdx.x == 0)
    ws[WS_PART + blockIdx.x] = psum[0] + psum[1] + psum[2] + psum[3];
}

// ---------------------------------------------------------------------------
// gather: out = x + (e - x). Block 0 additionally computes the loss from
// refine's mse partials + colkeys (all in ws, complete at kernel boundary).
__global__ __launch_bounds__(256) void vq_gather(const float* __restrict__ V,
                                                 const float* __restrict__ CB,
                                                 const unsigned* __restrict__ token,
                                                 const float* __restrict__ ws,
                                                 float* __restrict__ out) {
  int w = threadIdx.x >> 6, lane = threadIdx.x & 63;
  int row = blockIdx.x * 4 + w;
  int tok = (int)token[row];

  float4 e = *(const float4*)(CB + (size_t)tok * DIMS + lane * 4);
  float4 x = *(const float4*)(V + (size_t)row * DIMS + lane * 4);
  float4 o;
  o.x = x.x + (e.x - x.x); o.y = x.y + (e.y - x.y);
  o.z = x.z + (e.z - x.z); o.w = x.w + (e.w - x.w);
  *(float4*)(out + (size_t)row * DIMS + lane * 4) = o;

  if (blockIdx.x == 0) {
    __shared__ float psum[4];
    float s = 0.f;
    for (int i = threadIdx.x; i < 8192; i += 256) s += ws[WS_PART + i];
    const unsigned* ck = (const unsigned*)(ws + WS_COLKEY);
    float cs = 0.f;
    for (int i = threadIdx.x; i < KCODES; i += 256) cs += __uint_as_float(ck[i]);
    float v = s * (1.25f / 8388608.f) + cs * (0.1f / 4096.f);
    #pragma unroll
    for (int off = 32; off > 0; off >>= 1) v += __shfl_down(v, off, 64);
    if (lane == 0) psum[w] = v;
    __syncthreads();
    if (threadIdx.x == 0)
      out[8388608] = psum[0] + psum[1] + psum[2] + psum[3];
  }
}

// ---------------------------------------------------------------------------
extern "C" void kernel_launch(void* const* d_in, const int* in_sizes, int n_in,
                              void* d_out, int out_size, void* d_ws, size_t ws_size,
                              hipStream_t stream) {
  const float* V  = (const float*)d_in[0];   // [32768, 256]
  const float* CB = (const float*)d_in[1];   // [4096, 256]
  float* out = (float*)d_out;                // 8388608 emb + 1 loss
  float* ws  = (float*)d_ws;

  _Float16* Vh     = (_Float16*)out;                 // scratch in d_out (tiled)
  unsigned* candG  = (unsigned*)(out + 4194304);     // scratch in d_out (16 MB)
  unsigned* colkey = (unsigned*)(ws + WS_COLKEY);
  unsigned* token  = (unsigned*)(ws + WS_TOKEN);

  vq_prep<<<(M_ROWS + KCODES) / 4, 256, 0, stream>>>(V, CB, ws, out);
  vq_hh<<<8192, 256, 0, stream>>>(Vh, (const _Float16*)(ws + WS_CH),
                                  ws + WS_V2, ws + WS_C2, candG, colkey);
  vq_refine<<<M_ROWS / 4, 256, 0, stream>>>(V, CB, candG, token, ws);
  vq_gather<<<M_ROWS / 4, 256, 0, stream>>>(V, CB, token, ws, out);
}